// Round 1
// baseline (1408.066 us; speedup 1.0000x reference)
//
#include <hip/hip_runtime.h>
#include <hip/hip_bf16.h>

#define N_NODES 5000
#define E_EDGES 16000
#define B_Q 8
#define D_DIM 128
#define DD_DIM 64
#define D4 512
#define D2 256

// ws layout (float offsets)
#define OFF_HN   0
#define OFF_WDST 640000
#define OFF_VB   1280000
#define OFF_GE   1284096
#define OFF_M    17668096
#define OFF_Z    22788096
#define OFF_S    27908096

__device__ __forceinline__ float leaky(float x) { return x > 0.f ? x : 0.01f * x; }
__device__ __forceinline__ unsigned enc_f32(float f) {
    unsigned u = __float_as_uint(f);
    return (u & 0x80000000u) ? ~u : (u | 0x80000000u);
}
__device__ __forceinline__ float dec_f32(unsigned u) {
    unsigned i = (u & 0x80000000u) ? (u ^ 0x80000000u) : ~u;
    return __uint_as_float(i);
}
__device__ __forceinline__ int sgnk(int a, int b) { int d = a - b; return d > 0 ? 2 : (d == 0 ? 1 : 0); }

// ---------------- K1: node prep: h_n and w_dst = h_n*attn_i*attn_j ----------------
__global__ void k_node(const int* __restrict__ node_idx, const float* __restrict__ node_time,
                       const float* __restrict__ syn, const float* __restrict__ diae,
                       const float* __restrict__ diaw, const float* __restrict__ diab,
                       const float* __restrict__ attn_i, const float* __restrict__ attn_j,
                       float* __restrict__ h_n, float* __restrict__ w_dst) {
    int n = blockIdx.x, d = threadIdx.x;
    int nid = node_idx[n];
    float h = syn[nid * D_DIM + d];
    if (d >= DD_DIM) {
        int q = d - DD_DIM;
        h += diae[nid * DD_DIM + q] * sinf(diaw[nid * DD_DIM + q] * node_time[n] + diab[nid * DD_DIM + q]);
    }
    h_n[n * D_DIM + d] = h;
    w_dst[n * D_DIM + d] = h * attn_i[d] * attn_j[d];
}

// ---------------- K2: v_b[b][j] = batch_t2v[b] @ W1[D:,:] + b1 ----------------
__global__ void k_vb(const float* __restrict__ bt2v, const float* __restrict__ W1,
                     const float* __restrict__ b1, float* __restrict__ v_b) {
    int b = blockIdx.x, j = threadIdx.x;
    float acc = b1[j];
    for (int i = 0; i < D_DIM; ++i)
        acc = fmaf(bt2v[b * D_DIM + i], W1[(D_DIM + i) * D4 + j], acc);
    v_b[b * D4 + j] = acc;
}

// ---------------- K3: fused per-edge pipeline (2 edges x 8 queries / block) ----------------
// LDS float map (16384 = 64KB):
//   [0..255]        t2v[2][128]
//   [256..8447]     h1[16][512]      (later: x_ss@256[16][128], x_ee@2304, g@4352, part3@6400)
//   [8448..12543]   h2[16][256]      (also phase-2 partial staging)
//   [6400..14591]   phase-4 W tile (64 rows x 128) -- h1/h2 dead by then
__global__ __launch_bounds__(256) void k_edge(
    const int* __restrict__ src, const int* __restrict__ dst,
    const int* __restrict__ relation_type,
    const int* __restrict__ edge_start, const int* __restrict__ edge_end,
    const int* __restrict__ batch_start, const int* __restrict__ batch_end,
    const float* __restrict__ edge_t2v,
    const float* __restrict__ W1, const float* __restrict__ W2, const float* __restrict__ b2,
    const float* __restrict__ W3, const float* __restrict__ b3,
    const float* __restrict__ Wss, const float* __restrict__ bss,
    const float* __restrict__ Wee, const float* __restrict__ bee,
    const float* __restrict__ rel_embed,
    const float* __restrict__ h_n, const float* __restrict__ w_dst,
    const float* __restrict__ v_b,
    float* __restrict__ g_e, unsigned* __restrict__ m_ord) {
    __shared__ float sm[16384];
    const int t = threadIdx.x;
    const int e0 = blockIdx.x * 2;
    const int j0 = t & 127;
    const int ih = t >> 7;  // K-split half; also my edge group in phases 4/5

    // metadata (uniform)
    const int es0 = edge_start[e0], es1 = edge_start[e0 + 1];
    const int ed0 = edge_end[e0], ed1 = edge_end[e0 + 1];
    const int sr0 = src[e0], sr1 = src[e0 + 1];
    const int ds0 = dst[e0], ds1 = dst[e0 + 1];
    const int rt0 = relation_type[e0], rt1 = relation_type[e0 + 1];
    int bs[8], be[8];
#pragma unroll
    for (int b = 0; b < 8; ++b) { bs[b] = batch_start[b]; be[b] = batch_end[b]; }

    // ---- phase 1: stage t2v; u = t2v @ W1_top; h1 = relu(u + v_b)
    sm[t] = edge_t2v[(e0 + (t >> 7)) * D_DIM + (t & 127)];
    __syncthreads();
    {
        float a00 = 0.f, a01 = 0.f, a10 = 0.f, a11 = 0.f;
        for (int i = 0; i < 128; ++i) {
            float w0 = W1[i * D4 + t];
            float w1 = W1[i * D4 + t + 256];
            float x0 = sm[i], x1 = sm[128 + i];
            a00 = fmaf(x0, w0, a00); a01 = fmaf(x0, w1, a01);
            a10 = fmaf(x1, w0, a10); a11 = fmaf(x1, w1, a11);
        }
#pragma unroll
        for (int b = 0; b < 8; ++b) {
            float vb0 = v_b[b * D4 + t], vb1 = v_b[b * D4 + t + 256];
            sm[256 + (0 * 8 + b) * D4 + t] = fmaxf(a00 + vb0, 0.f);
            sm[256 + (0 * 8 + b) * D4 + t + 256] = fmaxf(a01 + vb1, 0.f);
            sm[256 + (1 * 8 + b) * D4 + t] = fmaxf(a10 + vb0, 0.f);
            sm[256 + (1 * 8 + b) * D4 + t + 256] = fmaxf(a11 + vb1, 0.f);
        }
    }
    __syncthreads();

    // ---- phase 2: h2 = relu(h1 @ W2 + b2), K split across ih, j-tile = 2
    {
        float acc[16][2];
#pragma unroll
        for (int p = 0; p < 16; ++p) { acc[p][0] = 0.f; acc[p][1] = 0.f; }
        const int ibase = ih * 256;
        for (int i4 = 0; i4 < 64; ++i4) {
            const int ib = ibase + i4 * 4;
            float w00 = W2[(ib + 0) * D2 + j0], w10 = W2[(ib + 0) * D2 + j0 + 128];
            float w01 = W2[(ib + 1) * D2 + j0], w11 = W2[(ib + 1) * D2 + j0 + 128];
            float w02 = W2[(ib + 2) * D2 + j0], w12 = W2[(ib + 2) * D2 + j0 + 128];
            float w03 = W2[(ib + 3) * D2 + j0], w13 = W2[(ib + 3) * D2 + j0 + 128];
#pragma unroll
            for (int p = 0; p < 16; ++p) {
                const float4 h = *(const float4*)&sm[256 + p * D4 + ib];
                acc[p][0] = fmaf(h.x, w00, fmaf(h.y, w01, fmaf(h.z, w02, fmaf(h.w, w03, acc[p][0]))));
                acc[p][1] = fmaf(h.x, w10, fmaf(h.y, w11, fmaf(h.z, w12, fmaf(h.w, w13, acc[p][1]))));
            }
        }
        __syncthreads();
        if (ih == 1) {
#pragma unroll
            for (int p = 0; p < 16; ++p) {
                sm[8448 + p * D2 + j0] = acc[p][0];
                sm[8448 + p * D2 + j0 + 128] = acc[p][1];
            }
        }
        __syncthreads();
        if (ih == 0) {
            float bb0 = b2[j0], bb1 = b2[j0 + 128];
#pragma unroll
            for (int p = 0; p < 16; ++p) {
                float v0 = fmaxf(acc[p][0] + sm[8448 + p * D2 + j0] + bb0, 0.f);
                float v1 = fmaxf(acc[p][1] + sm[8448 + p * D2 + j0 + 128] + bb1, 0.f);
                sm[8448 + p * D2 + j0] = v0;
                sm[8448 + p * D2 + j0 + 128] = v1;
            }
        }
    }
    __syncthreads();

    // ---- phase 3: tau = h2 @ W3 + b3 ; x_ss = h_n[src]+tau ; x_ee = rel+tau ; g = biases
    {
        float tacc[16];
#pragma unroll
        for (int p = 0; p < 16; ++p) tacc[p] = 0.f;
        const int ibase = ih * 128;
        for (int i4 = 0; i4 < 32; ++i4) {
            const int ib = ibase + i4 * 4;
            float w0 = W3[(ib + 0) * D_DIM + j0];
            float w1 = W3[(ib + 1) * D_DIM + j0];
            float w2 = W3[(ib + 2) * D_DIM + j0];
            float w3 = W3[(ib + 3) * D_DIM + j0];
#pragma unroll
            for (int p = 0; p < 16; ++p) {
                const float4 h = *(const float4*)&sm[8448 + p * D2 + ib];
                tacc[p] = fmaf(h.x, w0, fmaf(h.y, w1, fmaf(h.z, w2, fmaf(h.w, w3, tacc[p]))));
            }
        }
        __syncthreads();
        if (ih == 1) {
#pragma unroll
            for (int p = 0; p < 16; ++p) sm[6400 + p * D_DIM + j0] = tacc[p];
        }
        __syncthreads();
        if (ih == 0) {
            const float b3v = b3[j0];
#pragma unroll
            for (int p = 0; p < 16; ++p) {
                const int e = p >> 3, b = p & 7;
                float tau = tacc[p] + sm[6400 + p * D_DIM + j0] + b3v;
                const int srcn = e ? sr1 : sr0;
                const int rtn = e ? rt1 : rt0;
                const int kss = sgnk(e ? es1 : es0, bs[b]);
                const int kee = sgnk(e ? ed1 : ed0, be[b]);
                sm[256 + p * D_DIM + j0] = h_n[srcn * D_DIM + j0] + tau;
                sm[2304 + p * D_DIM + j0] = rel_embed[rtn * D_DIM + j0] + tau;
                sm[4352 + p * D_DIM + j0] = bss[kss * D_DIM + j0] + bee[kee * D_DIM + j0];
            }
        }
    }
    __syncthreads();

    // ---- phase 4: g += x_ss @ Wss[k_ss] + x_ee @ Wee[k_ee], k-outer with LDS W half-tiles
    int any_ss = 0, any_ee = 0;
#pragma unroll
    for (int b = 0; b < 8; ++b) {
        any_ss |= (1 << sgnk(es0, bs[b])) | (1 << sgnk(es1, bs[b]));
        any_ee |= (1 << sgnk(ed0, be[b])) | (1 << sgnk(ed1, be[b]));
    }
    const int mes = ih ? es1 : es0;
    const int med = ih ? ed1 : ed0;
    for (int pass = 0; pass < 2; ++pass) {
        const float* Wm = pass ? Wee : Wss;
        const int xbase = pass ? 2304 : 256;
        const int anym = pass ? any_ee : any_ss;
        for (int k = 0; k < 3; ++k) {
            const bool any = (anym >> k) & 1;
            for (int ihalf = 0; ihalf < 2; ++ihalf) {
                if (any) {
#pragma unroll
                    for (int q = 0; q < 8; ++q) {
                        const int idx = q * 1024 + t * 4;
                        *(float4*)&sm[6400 + idx] = *(const float4*)&Wm[k * 16384 + ihalf * 8192 + idx];
                    }
                }
                __syncthreads();
                if (any) {
#pragma unroll
                    for (int p8 = 0; p8 < 8; ++p8) {
                        const int myk = pass ? sgnk(med, be[p8]) : sgnk(mes, bs[p8]);
                        if (myk == k) {
                            const int p = ih * 8 + p8;
                            float acc = 0.f;
#pragma unroll
                            for (int i4 = 0; i4 < 16; ++i4) {
                                const float4 x = *(const float4*)&sm[xbase + p * D_DIM + ihalf * 64 + i4 * 4];
                                acc = fmaf(x.x, sm[6400 + (i4 * 4 + 0) * D_DIM + j0],
                                      fmaf(x.y, sm[6400 + (i4 * 4 + 1) * D_DIM + j0],
                                      fmaf(x.z, sm[6400 + (i4 * 4 + 2) * D_DIM + j0],
                                      fmaf(x.w, sm[6400 + (i4 * 4 + 3) * D_DIM + j0], acc))));
                            }
                            sm[4352 + p * D_DIM + j0] += acc;
                        }
                    }
                }
                __syncthreads();
            }
        }
    }

    // ---- phase 5: store g_e, score, segment-max via ordered-uint atomicMax
    {
        const int mydst = ih ? ds1 : ds0;
        const int mye = e0 + ih;
#pragma unroll
        for (int p8 = 0; p8 < 8; ++p8) {
            const int p = ih * 8 + p8;
            const float g = sm[4352 + p * D_DIM + j0];
            g_e[(mye * B_Q + p8) * D_DIM + j0] = g;
            float sc = leaky(w_dst[mydst * D_DIM + j0] * g);
            atomicMax(&m_ord[(mydst * B_Q + p8) * D_DIM + j0], enc_f32(sc));
        }
    }
}

// ---------------- K4: s = exp(score - m); z += s; S += s*g ----------------
__global__ __launch_bounds__(256) void k_softmax_acc(
    const int* __restrict__ dst, const float* __restrict__ g_e,
    const float* __restrict__ w_dst, const unsigned* __restrict__ m_ord,
    float* __restrict__ z, float* __restrict__ S) {
    int idx = blockIdx.x * 256 + threadIdx.x;
    int e = idx >> 10, rem = idx & 1023, b = rem >> 7, d = rem & 127;
    float g = g_e[idx];
    int dn = dst[e];
    float sc = leaky(w_dst[dn * D_DIM + d] * g);
    int o = (dn * B_Q + b) * D_DIM + d;
    float m = dec_f32(m_ord[o]);
    float s = expf(sc - m);
    atomicAdd(&z[o], s);
    atomicAdd(&S[o], s * g);
}

// ---------------- K5: out = leaky(S / (z + 1e-16)) ----------------
__global__ void k_final(const float* __restrict__ z, const float* __restrict__ S,
                        float* __restrict__ out) {
    int idx = blockIdx.x * 256 + threadIdx.x;
    float r = S[idx] / (z[idx] + 1e-16f);
    out[idx] = leaky(r);
}

extern "C" void kernel_launch(void* const* d_in, const int* in_sizes, int n_in,
                              void* d_out, int out_size, void* d_ws, size_t ws_size,
                              hipStream_t stream) {
    const int* src = (const int*)d_in[0];
    const int* dst = (const int*)d_in[1];
    const int* node_idx = (const int*)d_in[2];
    const int* rel = (const int*)d_in[3];
    const int* es = (const int*)d_in[4];
    const int* ee = (const int*)d_in[5];
    const int* bs = (const int*)d_in[6];
    const int* be = (const int*)d_in[7];
    const float* node_time = (const float*)d_in[8];
    const float* edge_t2v = (const float*)d_in[9];
    const float* batch_t2v = (const float*)d_in[10];
    const float* syn = (const float*)d_in[11];
    const float* diae = (const float*)d_in[12];
    const float* diaw = (const float*)d_in[13];
    const float* diab = (const float*)d_in[14];
    const float* rele = (const float*)d_in[15];
    const float* W1 = (const float*)d_in[16];
    const float* b1 = (const float*)d_in[17];
    const float* W2 = (const float*)d_in[18];
    const float* b2 = (const float*)d_in[19];
    const float* W3 = (const float*)d_in[20];
    const float* b3 = (const float*)d_in[21];
    const float* Wss = (const float*)d_in[22];
    const float* bss = (const float*)d_in[23];
    const float* Wee = (const float*)d_in[24];
    const float* bee = (const float*)d_in[25];
    const float* ai = (const float*)d_in[26];
    const float* aj = (const float*)d_in[27];

    float* ws = (float*)d_ws;
    float* h_n = ws + OFF_HN;
    float* wdst = ws + OFF_WDST;
    float* v_b = ws + OFF_VB;
    float* g_e = ws + OFF_GE;
    unsigned* m_ord = (unsigned*)(ws + OFF_M);
    float* z = ws + OFF_Z;
    float* S = ws + OFF_S;
    float* out = (float*)d_out;

    // zero m/z/S (contiguous)
    hipMemsetAsync(ws + OFF_M, 0, (size_t)3 * N_NODES * B_Q * D_DIM * 4, stream);

    k_node<<<N_NODES, 128, 0, stream>>>(node_idx, node_time, syn, diae, diaw, diab, ai, aj, h_n, wdst);
    k_vb<<<B_Q, 512, 0, stream>>>(batch_t2v, W1, b1, v_b);
    k_edge<<<E_EDGES / 2, 256, 0, stream>>>(src, dst, rel, es, ee, bs, be, edge_t2v,
                                            W1, W2, b2, W3, b3, Wss, bss, Wee, bee, rele,
                                            h_n, wdst, v_b, g_e, m_ord);
    k_softmax_acc<<<E_EDGES * B_Q * D_DIM / 256, 256, 0, stream>>>(dst, g_e, wdst, m_ord, z, S);
    k_final<<<N_NODES * B_Q * D_DIM / 256, 256, 0, stream>>>(z, S, out);
}

// Round 2
// 553.286 us; speedup vs baseline: 2.5449x; 2.5449x over previous
//
#include <hip/hip_runtime.h>
#include <hip/hip_bf16.h>

typedef __attribute__((ext_vector_type(8))) short short8;
typedef __attribute__((ext_vector_type(4))) float f32x4;

#define N_NODES 5000
#define E_EDGES 16000
#define B_Q 8
#define D_DIM 128

// ---- ws layout (float offsets), liveness-overlapped ----
#define OFF_M     0           // uint  5,120,000   (gemm4 -> softmax; overlaps dead h2)
#define OFF_Z     5120000     // f32   5,120,000
#define OFF_S     10240000    // f32   5,120,000
#define OFF_H2    0           // bf16 32,768,000   (gemm2 -> gemm3)
#define OFF_U     16384000    // bf16  8,192,000   (gemm1 -> gemm2)
#define OFF_XSS   16384000    // bf16 16,384,000   (gemm3 -> gemm4; overlaps dead u)
#define OFF_XEE   24576000    // bf16 16,384,000
#define OFF_G     32768000    // bf16 16,384,000   (gemm4 -> softmax)
#define OFF_HN    40960000    // f32     640,000
#define OFF_WDST  41600000    // f32     640,000
#define OFF_VB    42240000    // f32       4,096
#define OFF_W2T   42244096    // bf16    131,072
#define OFF_W3T   42309632    // bf16     32,768
#define OFF_WALLT 42326016    // bf16     98,304
#define OFF_W1T   42375168    // bf16     65,536
// end = 42,407,936 floats = 169.6 MB

__device__ __forceinline__ float leaky(float x) { return x > 0.f ? x : 0.01f * x; }
__device__ __forceinline__ unsigned enc_f32(float f) {
    unsigned u = __float_as_uint(f);
    return (u & 0x80000000u) ? ~u : (u | 0x80000000u);
}
__device__ __forceinline__ float dec_f32(unsigned u) {
    unsigned i = (u & 0x80000000u) ? (u ^ 0x80000000u) : ~u;
    return __uint_as_float(i);
}
__device__ __forceinline__ int sgnk(int a, int b) { int d = a - b; return d > 0 ? 2 : (d == 0 ? 1 : 0); }
__device__ __forceinline__ unsigned f2bfu(float f) {  // RNE fp32->bf16 (no NaNs in this workload)
    unsigned u = __float_as_uint(f);
    return (u + 0x7fffu + ((u >> 16) & 1u)) >> 16;
}
__device__ __forceinline__ unsigned pk2(float a, float b) { return f2bfu(a) | (f2bfu(b) << 16); }
__device__ __forceinline__ float bflo(unsigned w) { return __uint_as_float(w << 16); }
__device__ __forceinline__ float bfhi(unsigned w) { return __uint_as_float(w & 0xffff0000u); }
__device__ __forceinline__ float bf2f(unsigned short s) { return __uint_as_float(((unsigned)s) << 16); }

// T2 swizzle: 16KB tile, 128 rows x 128B; byte ^= (row&7)<<4
#define SWZB(row, lb) (((row) << 7) + ((lb) ^ (((row) & 7) << 4)))

// ---------------- tiny prep kernels ----------------
__global__ void k_wprep(const float* __restrict__ W1, const float* __restrict__ W2,
                        const float* __restrict__ W3, const float* __restrict__ Wss,
                        const float* __restrict__ Wee,
                        ushort* __restrict__ W1t, ushort* __restrict__ W2t,
                        ushort* __restrict__ W3t, ushort* __restrict__ Wallt) {
    int tid = blockIdx.x * 256 + threadIdx.x;
    if (tid < 131072) {                       // W2t[n][k] = W2[k][n], 256x512
        int n = tid >> 9, k = tid & 511;
        W2t[tid] = (ushort)f2bfu(W2[k * 256 + n]);
    } else if (tid < 163840) {                // W3t[n][k] = W3[k][n], 128x256
        int q = tid - 131072; int n = q >> 8, k = q & 255;
        W3t[q] = (ushort)f2bfu(W3[k * 128 + n]);
    } else if (tid < 262144) {                // Wallt[c][n][k], c<6 = {ss0..2, ee0..2}
        int q = tid - 163840; int c = q >> 14, rr = q & 16383, n = rr >> 7, k = rr & 127;
        const float* Wm = (c < 3) ? Wss : Wee; int cc = (c < 3) ? c : c - 3;
        Wallt[q] = (ushort)f2bfu(Wm[cc * 16384 + k * 128 + n]);
    } else if (tid < 327680) {                // W1t[n][k] = W1[k][n], 512x128 (top half)
        int q = tid - 262144; int n = q >> 7, k = q & 127;
        W1t[q] = (ushort)f2bfu(W1[k * 512 + n]);
    }
}

__global__ void k_node(const int* __restrict__ node_idx, const float* __restrict__ node_time,
                       const float* __restrict__ syn, const float* __restrict__ diae,
                       const float* __restrict__ diaw, const float* __restrict__ diab,
                       const float* __restrict__ attn_i, const float* __restrict__ attn_j,
                       float* __restrict__ h_n, float* __restrict__ w_dst) {
    int n = blockIdx.x, d = threadIdx.x;
    int nid = node_idx[n];
    float h = syn[nid * D_DIM + d];
    if (d >= 64) {
        int q = d - 64;
        h += diae[nid * 64 + q] * sinf(diaw[nid * 64 + q] * node_time[n] + diab[nid * 64 + q]);
    }
    h_n[n * D_DIM + d] = h;
    w_dst[n * D_DIM + d] = h * attn_i[d] * attn_j[d];
}

__global__ void k_vb(const float* __restrict__ bt2v, const float* __restrict__ W1,
                     const float* __restrict__ b1, float* __restrict__ v_b) {
    int b = blockIdx.x, j = threadIdx.x;
    float acc = b1[j];
    for (int i = 0; i < 128; ++i)
        acc = fmaf(bt2v[b * 128 + i], W1[(128 + i) * 512 + j], acc);
    v_b[b * 512 + j] = acc;
}

// ---------------- shared MFMA compute phase ----------------
__device__ __forceinline__ void mfma_step(const unsigned char* lA, const unsigned char* lB,
                                          int wr, int wc, int lane, f32x4 (&acc)[4][4]) {
    const int row0 = wr * 64 + (lane & 15);
    const int nrow0 = wc * 64 + (lane & 15);
    const int kslot = (lane >> 4) * 16;   // byte offset of this lane's 8-elem k group
#pragma unroll
    for (int ks = 0; ks < 2; ++ks) {
        short8 a[4], b[4];
#pragma unroll
        for (int m = 0; m < 4; ++m)
            a[m] = *(const short8*)(lA + SWZB(row0 + m * 16, ks * 64 + kslot));
#pragma unroll
        for (int n = 0; n < 4; ++n)
            b[n] = *(const short8*)(lB + SWZB(nrow0 + n * 16, ks * 64 + kslot));
#pragma unroll
        for (int m = 0; m < 4; ++m)
#pragma unroll
            for (int n = 0; n < 4; ++n)
                acc[m][n] = __builtin_amdgcn_mfma_f32_16x16x32_bf16(a[m], b[n], acc[m][n], 0, 0, 0);
    }
}

// ---------------- GEMM1: u = edge_t2v @ W1_top  (M=16000,K=128,N=512) ----------------
__global__ __launch_bounds__(256) void k_gemm1(const float* __restrict__ et2v,
                                               const ushort* __restrict__ W1t,
                                               ushort* __restrict__ u) {
    __shared__ __align__(16) unsigned char lA[16384];
    __shared__ __align__(16) unsigned char lB[16384];
    const int t = threadIdx.x;
    const int m0 = (blockIdx.x >> 2) * 128;
    const int n0 = (blockIdx.x & 3) * 128;
    const int lane = t & 63, wid = t >> 6, wr = wid >> 1, wc = wid & 1;
    const int srow = t >> 1, koff = (t & 1) * 32, lb0 = (t & 1) * 64;
    f32x4 acc[4][4] = {};
    for (int step = 0; step < 2; ++step) {
        const float4* ap = (const float4*)(et2v + (size_t)(m0 + srow) * 128 + step * 64 + koff);
#pragma unroll
        for (int i = 0; i < 4; ++i) {
            float4 x0 = ap[2 * i], x1 = ap[2 * i + 1];
            *(uint4*)&lA[SWZB(srow, lb0 + i * 16)] =
                make_uint4(pk2(x0.x, x0.y), pk2(x0.z, x0.w), pk2(x1.x, x1.y), pk2(x1.z, x1.w));
        }
        const uint4* bp = (const uint4*)(W1t + (size_t)(n0 + srow) * 128 + step * 64 + koff);
#pragma unroll
        for (int i = 0; i < 4; ++i) *(uint4*)&lB[SWZB(srow, lb0 + i * 16)] = bp[i];
        __syncthreads();
        mfma_step(lA, lB, wr, wc, lane, acc);
        __syncthreads();
    }
    const int rbase = wr * 64 + ((lane >> 4) << 2);
    const int cbase = n0 + wc * 64 + (lane & 15);
#pragma unroll
    for (int mm = 0; mm < 4; ++mm)
#pragma unroll
        for (int nn = 0; nn < 4; ++nn)
#pragma unroll
            for (int i = 0; i < 4; ++i)
                u[(size_t)(m0 + rbase + mm * 16 + i) * 512 + cbase + nn * 16] =
                    (ushort)f2bfu(acc[mm][nn][i]);
}

// ---------------- GEMM2: h2 = relu(relu(u+v_b) @ W2 + b2)  (M=128000,K=512,N=256) ----------------
__global__ __launch_bounds__(256) void k_gemm2(const ushort* __restrict__ u,
                                               const float* __restrict__ v_b,
                                               const ushort* __restrict__ W2t,
                                               const float* __restrict__ b2,
                                               ushort* __restrict__ h2) {
    __shared__ __align__(16) unsigned char lA[16384];
    __shared__ __align__(16) unsigned char lB[16384];
    const int t = threadIdx.x;
    const int m0 = (blockIdx.x >> 1) * 128;
    const int n0 = (blockIdx.x & 1) * 128;
    const int lane = t & 63, wid = t >> 6, wr = wid >> 1, wc = wid & 1;
    const int srow = t >> 1, koff = (t & 1) * 32, lb0 = (t & 1) * 64;
    const int ae = (m0 + srow) >> 3, ab = (m0 + srow) & 7;
    f32x4 acc[4][4] = {};
    for (int step = 0; step < 8; ++step) {
        const int k0 = step * 64 + koff;
        const uint4* up = (const uint4*)(u + (size_t)ae * 512 + k0);
        const float4* vp = (const float4*)(v_b + ab * 512 + k0);
#pragma unroll
        for (int i = 0; i < 4; ++i) {
            uint4 uv = up[i];
            float4 va = vp[2 * i], vb4 = vp[2 * i + 1];
            unsigned r0 = pk2(fmaxf(bflo(uv.x) + va.x, 0.f), fmaxf(bfhi(uv.x) + va.y, 0.f));
            unsigned r1 = pk2(fmaxf(bflo(uv.y) + va.z, 0.f), fmaxf(bfhi(uv.y) + va.w, 0.f));
            unsigned r2 = pk2(fmaxf(bflo(uv.z) + vb4.x, 0.f), fmaxf(bfhi(uv.z) + vb4.y, 0.f));
            unsigned r3 = pk2(fmaxf(bflo(uv.w) + vb4.z, 0.f), fmaxf(bfhi(uv.w) + vb4.w, 0.f));
            *(uint4*)&lA[SWZB(srow, lb0 + i * 16)] = make_uint4(r0, r1, r2, r3);
        }
        const uint4* bp = (const uint4*)(W2t + (size_t)(n0 + srow) * 512 + k0);
#pragma unroll
        for (int i = 0; i < 4; ++i) *(uint4*)&lB[SWZB(srow, lb0 + i * 16)] = bp[i];
        __syncthreads();
        mfma_step(lA, lB, wr, wc, lane, acc);
        __syncthreads();
    }
    const int rbase = wr * 64 + ((lane >> 4) << 2);
    const int cbase = n0 + wc * 64 + (lane & 15);
#pragma unroll
    for (int nn = 0; nn < 4; ++nn) {
        const int gc = cbase + nn * 16;
        const float bb = b2[gc];
#pragma unroll
        for (int mm = 0; mm < 4; ++mm)
#pragma unroll
            for (int i = 0; i < 4; ++i)
                h2[(size_t)(m0 + rbase + mm * 16 + i) * 256 + gc] =
                    (ushort)f2bfu(fmaxf(acc[mm][nn][i] + bb, 0.f));
    }
}

// ---------------- GEMM3: tau = h2@W3+b3; x_ss = h_n[src]+tau; x_ee = rel+tau ----------------
__global__ __launch_bounds__(256) void k_gemm3(const ushort* __restrict__ h2,
                                               const ushort* __restrict__ W3t,
                                               const float* __restrict__ b3,
                                               const int* __restrict__ src,
                                               const int* __restrict__ rtyp,
                                               const float* __restrict__ h_n,
                                               const float* __restrict__ rel_embed,
                                               ushort* __restrict__ xss,
                                               ushort* __restrict__ xee) {
    __shared__ __align__(16) unsigned char lA[16384];
    __shared__ __align__(16) unsigned char lB[16384];
    const int t = threadIdx.x;
    const int m0 = blockIdx.x * 128;
    const int lane = t & 63, wid = t >> 6, wr = wid >> 1, wc = wid & 1;
    const int srow = t >> 1, koff = (t & 1) * 32, lb0 = (t & 1) * 64;
    f32x4 acc[4][4] = {};
    for (int step = 0; step < 4; ++step) {
        const int k0 = step * 64 + koff;
        const uint4* ap = (const uint4*)(h2 + (size_t)(m0 + srow) * 256 + k0);
#pragma unroll
        for (int i = 0; i < 4; ++i) *(uint4*)&lA[SWZB(srow, lb0 + i * 16)] = ap[i];
        const uint4* bp = (const uint4*)(W3t + (size_t)srow * 256 + k0);
#pragma unroll
        for (int i = 0; i < 4; ++i) *(uint4*)&lB[SWZB(srow, lb0 + i * 16)] = bp[i];
        __syncthreads();
        mfma_step(lA, lB, wr, wc, lane, acc);
        __syncthreads();
    }
    const int rbase = wr * 64 + ((lane >> 4) << 2);
    const int cbase = wc * 64 + (lane & 15);
#pragma unroll
    for (int mm = 0; mm < 4; ++mm)
#pragma unroll
        for (int i = 0; i < 4; ++i) {
            const int gr = m0 + rbase + mm * 16 + i;
            const int e = gr >> 3;
            const int se = src[e], rr = rtyp[e];
#pragma unroll
            for (int nn = 0; nn < 4; ++nn) {
                const int gc = cbase + nn * 16;
                const float tau = acc[mm][nn][i] + b3[gc];
                xss[(size_t)gr * 128 + gc] = (ushort)f2bfu(h_n[se * 128 + gc] + tau);
                xee[(size_t)gr * 128 + gc] = (ushort)f2bfu(rel_embed[rr * 128 + gc] + tau);
            }
        }
}

// ---------------- GEMM4: g = masked GEMMs + biases; score; segment max ----------------
__global__ __launch_bounds__(256) void k_gemm4(const ushort* __restrict__ xss,
                                               const ushort* __restrict__ xee,
                                               const ushort* __restrict__ Wallt,
                                               const float* __restrict__ bss,
                                               const float* __restrict__ bee,
                                               const int* __restrict__ edge_start,
                                               const int* __restrict__ edge_end,
                                               const int* __restrict__ batch_start,
                                               const int* __restrict__ batch_end,
                                               const int* __restrict__ dst,
                                               const float* __restrict__ wdst,
                                               ushort* __restrict__ g_e,
                                               unsigned* __restrict__ m_ord) {
    __shared__ __align__(16) unsigned char lA[16384];
    __shared__ __align__(16) unsigned char lB[16384];
    __shared__ int selss_s[128], selee_s[128], dst_s[128];
    __shared__ int am_s;
    const int t = threadIdx.x;
    const int m0 = blockIdx.x * 128;
    const int lane = t & 63, wid = t >> 6, wr = wid >> 1, wc = wid & 1;
    const int srow = t >> 1, koff = (t & 1) * 32, lb0 = (t & 1) * 64;
    if (t == 0) am_s = 0;
    __syncthreads();
    if (t < 128) {
        const int gr = m0 + t, e = gr >> 3, b = gr & 7;
        const int ss = sgnk(edge_start[e], batch_start[b]);
        const int se = sgnk(edge_end[e], batch_end[b]);
        selss_s[t] = ss; selee_s[t] = se; dst_s[t] = dst[e];
        atomicOr(&am_s, (1 << ss) | (8 << se));
    }
    __syncthreads();
    const int am = am_s;
    f32x4 acc[4][4] = {};
    for (int step = 0; step < 12; ++step) {
        const int c = step >> 1;
        if (!((am >> c) & 1)) continue;   // block-uniform skip
        const int m3 = (c < 3) ? c : c - 3;
        const ushort* xsrc = (c < 3) ? xss : xee;
        const int sel = (c < 3) ? selss_s[srow] : selee_s[srow];
        const bool on = (sel == m3);
        const uint4* ap = (const uint4*)(xsrc + (size_t)(m0 + srow) * 128 + (step & 1) * 64 + koff);
#pragma unroll
        for (int i = 0; i < 4; ++i) {
            uint4 v = make_uint4(0u, 0u, 0u, 0u);
            if (on) v = ap[i];
            *(uint4*)&lA[SWZB(srow, lb0 + i * 16)] = v;
        }
        const uint4* bp = (const uint4*)(Wallt + (size_t)c * 16384 + (size_t)srow * 128 + (step & 1) * 64 + koff);
#pragma unroll
        for (int i = 0; i < 4; ++i) *(uint4*)&lB[SWZB(srow, lb0 + i * 16)] = bp[i];
        __syncthreads();
        mfma_step(lA, lB, wr, wc, lane, acc);
        __syncthreads();
    }
    const int rbase = wr * 64 + ((lane >> 4) << 2);
    const int cbase = wc * 64 + (lane & 15);
#pragma unroll
    for (int mm = 0; mm < 4; ++mm)
#pragma unroll
        for (int i = 0; i < 4; ++i) {
            const int r = rbase + mm * 16 + i;
            const int gr = m0 + r, b = gr & 7;
            const int dn = dst_s[r], ss = selss_s[r], se = selee_s[r];
#pragma unroll
            for (int nn = 0; nn < 4; ++nn) {
                const int gc = cbase + nn * 16;
                const float g = acc[mm][nn][i] + bss[ss * 128 + gc] + bee[se * 128 + gc];
                const unsigned gb = f2bfu(g);
                g_e[(size_t)gr * 128 + gc] = (ushort)gb;
                const float sc = leaky(wdst[dn * 128 + gc] * __uint_as_float(gb << 16));
                atomicMax(&m_ord[((size_t)dn * 8 + b) * 128 + gc], enc_f32(sc));
            }
        }
}

// ---------------- softmax accumulate + finalize ----------------
__global__ __launch_bounds__(256) void k_softmax_acc(const int* __restrict__ dst,
                                                     const ushort* __restrict__ g_e,
                                                     const float* __restrict__ w_dst,
                                                     const unsigned* __restrict__ m_ord,
                                                     float* __restrict__ z, float* __restrict__ S) {
    int idx = blockIdx.x * 256 + threadIdx.x;
    int e = idx >> 10, b = (idx >> 7) & 7, d = idx & 127;
    float g = bf2f(g_e[idx]);
    int dn = dst[e];
    float sc = leaky(w_dst[dn * 128 + d] * g);
    int o = (dn * 8 + b) * 128 + d;
    float m = dec_f32(m_ord[o]);
    float s = expf(sc - m);
    atomicAdd(&z[o], s);
    atomicAdd(&S[o], s * g);
}

__global__ void k_final(const float* __restrict__ z, const float* __restrict__ S,
                        float* __restrict__ out) {
    int idx = blockIdx.x * 256 + threadIdx.x;
    float r = S[idx] / (z[idx] + 1e-16f);
    out[idx] = leaky(r);
}

extern "C" void kernel_launch(void* const* d_in, const int* in_sizes, int n_in,
                              void* d_out, int out_size, void* d_ws, size_t ws_size,
                              hipStream_t stream) {
    const int* src = (const int*)d_in[0];
    const int* dst = (const int*)d_in[1];
    const int* node_idx = (const int*)d_in[2];
    const int* rel = (const int*)d_in[3];
    const int* es = (const int*)d_in[4];
    const int* eend = (const int*)d_in[5];
    const int* bs = (const int*)d_in[6];
    const int* be = (const int*)d_in[7];
    const float* node_time = (const float*)d_in[8];
    const float* edge_t2v = (const float*)d_in[9];
    const float* batch_t2v = (const float*)d_in[10];
    const float* syn = (const float*)d_in[11];
    const float* diae = (const float*)d_in[12];
    const float* diaw = (const float*)d_in[13];
    const float* diab = (const float*)d_in[14];
    const float* rele = (const float*)d_in[15];
    const float* W1 = (const float*)d_in[16];
    const float* b1 = (const float*)d_in[17];
    const float* W2 = (const float*)d_in[18];
    const float* b2 = (const float*)d_in[19];
    const float* W3 = (const float*)d_in[20];
    const float* b3 = (const float*)d_in[21];
    const float* Wss = (const float*)d_in[22];
    const float* bss = (const float*)d_in[23];
    const float* Wee = (const float*)d_in[24];
    const float* bee = (const float*)d_in[25];
    const float* ai = (const float*)d_in[26];
    const float* aj = (const float*)d_in[27];

    float* ws = (float*)d_ws;
    unsigned* m_ord = (unsigned*)(ws + OFF_M);
    float* z = ws + OFF_Z;
    float* S = ws + OFF_S;
    ushort* h2 = (ushort*)(ws + OFF_H2);
    ushort* u = (ushort*)(ws + OFF_U);
    ushort* xss = (ushort*)(ws + OFF_XSS);
    ushort* xee = (ushort*)(ws + OFF_XEE);
    ushort* g_e = (ushort*)(ws + OFF_G);
    float* h_n = ws + OFF_HN;
    float* wdst = ws + OFF_WDST;
    float* v_b = ws + OFF_VB;
    ushort* W2t = (ushort*)(ws + OFF_W2T);
    ushort* W3t = (ushort*)(ws + OFF_W3T);
    ushort* Wallt = (ushort*)(ws + OFF_WALLT);
    ushort* W1t = (ushort*)(ws + OFF_W1T);
    float* out = (float*)d_out;

    k_wprep<<<1280, 256, 0, stream>>>(W1, W2, W3, Wss, Wee, W1t, W2t, W3t, Wallt);
    k_node<<<N_NODES, 128, 0, stream>>>(node_idx, node_time, syn, diae, diaw, diab, ai, aj, h_n, wdst);
    k_vb<<<B_Q, 512, 0, stream>>>(batch_t2v, W1, b1, v_b);
    k_gemm1<<<500, 256, 0, stream>>>(edge_t2v, W1t, u);
    k_gemm2<<<2000, 256, 0, stream>>>(u, v_b, W2t, b2, h2);
    k_gemm3<<<1000, 256, 0, stream>>>(h2, W3t, b3, src, rel, h_n, rele, xss, xee);
    // h2 region now dead: zero m_ord / z / S in one shot
    hipMemsetAsync(d_ws, 0, (size_t)15360000 * 4, stream);
    k_gemm4<<<1000, 256, 0, stream>>>(xss, xee, Wallt, bss, bee, es, eend, bs, be, dst, wdst, g_e, m_ord);
    k_softmax_acc<<<E_EDGES * B_Q * D_DIM / 256, 256, 0, stream>>>(dst, g_e, wdst, m_ord, z, S);
    k_final<<<N_NODES * B_Q * D_DIM / 256, 256, 0, stream>>>(z, S, out);
}

// Round 4
// 409.720 us; speedup vs baseline: 3.4367x; 1.3504x over previous
//
#include <hip/hip_runtime.h>
#include <hip/hip_bf16.h>

typedef __attribute__((ext_vector_type(8))) short short8;
typedef __attribute__((ext_vector_type(4))) float f32x4;

#define N_NODES 5000
#define E_EDGES 16000
#define B_Q 8
#define D_DIM 128

// ---- ws layout (float offsets), liveness-overlapped ----
#define OFF_H2    0            // bf16 32,768,000 elems (gemm2 -> gemm3)
#define OFF_U     16384000     // bf16  8,192,000 (gemm1 -> gemm2)
#define OFF_XSS   16384000     // bf16 16,384,000 (gemm3 -> gemm4; overlaps dead u)
#define OFF_XEE   24576000     // bf16 16,384,000
#define OFF_G     32768000     // bf16 16,384,000 (gemm4 -> segsm)
#define OFF_HN    40960000     // f32 640,000
#define OFF_WDST  41600000     // f32 640,000
#define OFF_VB    42240000     // f32 4,096
#define OFF_W2T   42244096     // bf16 131,072
#define OFF_W3T   42309632     // bf16 32,768
#define OFF_WALLT 42326016     // bf16 98,304
#define OFF_W1T   42375168     // bf16 65,536
#define OFF_CNT   42407936     // int 5,000
#define OFF_ROWP  42412936     // int 5,001
#define OFF_CUR   42417937     // int 5,000
#define OFF_ECSR  42422937     // int 16,000
// end = 42,438,937 floats = 169.8 MB

__device__ __forceinline__ float leaky(float x) { return x > 0.f ? x : 0.01f * x; }
__device__ __forceinline__ int sgnk(int a, int b) { int d = a - b; return d > 0 ? 2 : (d == 0 ? 1 : 0); }
__device__ __forceinline__ unsigned short f2bf(float f) {   // HW RNE cvt (compiler packs pairs)
    __hip_bfloat16 h = __float2bfloat16(f);
    unsigned short r; __builtin_memcpy(&r, &h, 2); return r;
}
__device__ __forceinline__ unsigned pk2(float a, float b) {
    return (unsigned)f2bf(a) | ((unsigned)f2bf(b) << 16);
}
__device__ __forceinline__ float bflo(unsigned w) { return __uint_as_float(w << 16); }
__device__ __forceinline__ float bfhi(unsigned w) { return __uint_as_float(w & 0xffff0000u); }
__device__ __forceinline__ float bf2f(unsigned short s) { return __uint_as_float(((unsigned)s) << 16); }

// T2 swizzle: rows of 128 B; byte ^= (row&7)<<4
#define SWZB(row, lb) (((row) << 7) + ((lb) ^ (((row) & 7) << 4)))

// ---------------- prep kernels ----------------
__global__ void k_wprep(const float* __restrict__ W1, const float* __restrict__ W2,
                        const float* __restrict__ W3, const float* __restrict__ Wss,
                        const float* __restrict__ Wee,
                        ushort* __restrict__ W1t, ushort* __restrict__ W2t,
                        ushort* __restrict__ W3t, ushort* __restrict__ Wallt) {
    int tid = blockIdx.x * 256 + threadIdx.x;
    if (tid < 131072) {                       // W2t[n][k] = W2[k][n], 256x512
        int n = tid >> 9, k = tid & 511;
        W2t[tid] = f2bf(W2[k * 256 + n]);
    } else if (tid < 163840) {                // W3t[n][k] = W3[k][n], 128x256
        int q = tid - 131072; int n = q >> 8, k = q & 255;
        W3t[q] = f2bf(W3[k * 128 + n]);
    } else if (tid < 262144) {                // Wallt[c][n][k], c = {ss0..2, ee0..2}
        int q = tid - 163840; int c = q >> 14, rr = q & 16383, n = rr >> 7, k = rr & 127;
        const float* Wm = (c < 3) ? Wss : Wee; int cc = (c < 3) ? c : c - 3;
        Wallt[q] = f2bf(Wm[cc * 16384 + k * 128 + n]);
    } else if (tid < 327680) {                // W1t[n][k] = W1[k][n], 512x128 (top half)
        int q = tid - 262144; int n = q >> 7, k = q & 127;
        W1t[q] = f2bf(W1[k * 512 + n]);
    }
}

__global__ void k_node(const int* __restrict__ node_idx, const float* __restrict__ node_time,
                       const float* __restrict__ syn, const float* __restrict__ diae,
                       const float* __restrict__ diaw, const float* __restrict__ diab,
                       const float* __restrict__ attn_i, const float* __restrict__ attn_j,
                       float* __restrict__ h_n, float* __restrict__ w_dst) {
    int n = blockIdx.x, d = threadIdx.x;
    int nid = node_idx[n];
    float h = syn[nid * D_DIM + d];
    if (d >= 64) {
        int q = d - 64;
        h += diae[nid * 64 + q] * sinf(diaw[nid * 64 + q] * node_time[n] + diab[nid * 64 + q]);
    }
    h_n[n * D_DIM + d] = h;
    w_dst[n * D_DIM + d] = h * attn_i[d] * attn_j[d];
}

__global__ void k_vb(const float* __restrict__ bt2v, const float* __restrict__ W1,
                     const float* __restrict__ b1, float* __restrict__ v_b) {
    int b = blockIdx.x, j = threadIdx.x;
    float acc = b1[j];
    for (int i = 0; i < 128; ++i)
        acc = fmaf(bt2v[b * 128 + i], W1[(128 + i) * 512 + j], acc);
    v_b[b * 512 + j] = acc;
}

// ---------------- CSR build ----------------
__global__ void k_count(const int* __restrict__ dst, int* __restrict__ cnt) {
    int e = blockIdx.x * 256 + threadIdx.x;
    if (e < E_EDGES) atomicAdd(&cnt[dst[e]], 1);
}

__global__ void k_scan(const int* __restrict__ cnt, int* __restrict__ rowptr,
                       int* __restrict__ cursor) {
    __shared__ int part[256];
    const int t = threadIdx.x;
    const int i0 = t * 20, i1 = min(N_NODES, i0 + 20);
    int s = 0;
    for (int i = i0; i < i1; ++i) s += cnt[i];
    part[t] = s;
    __syncthreads();
    for (int off = 1; off < 256; off <<= 1) {
        int v = (t >= off) ? part[t - off] : 0;
        __syncthreads();
        part[t] += v;
        __syncthreads();
    }
    int run = (t > 0) ? part[t - 1] : 0;
    for (int i = i0; i < i1; ++i) { rowptr[i] = run; cursor[i] = run; run += cnt[i]; }
    if (i0 < N_NODES && i1 == N_NODES) rowptr[N_NODES] = run;
}

__global__ void k_scatter(const int* __restrict__ dst, int* __restrict__ cursor,
                          int* __restrict__ ecsr) {
    int e = blockIdx.x * 256 + threadIdx.x;
    if (e < E_EDGES) {
        int p = atomicAdd(&cursor[dst[e]], 1);
        ecsr[p] = e;
    }
}

// ---------------- shared MFMA compute (4x4 fragments) ----------------
__device__ __forceinline__ void mfma_step(const unsigned char* lA, const unsigned char* lB,
                                          int wr, int wc, int lane, f32x4 (&acc)[4][4]) {
    const int row0 = wr * 64 + (lane & 15);
    const int nrow0 = wc * 64 + (lane & 15);
    const int kslot = (lane >> 4) * 16;
#pragma unroll
    for (int ks = 0; ks < 2; ++ks) {
        short8 a[4], b[4];
#pragma unroll
        for (int m = 0; m < 4; ++m)
            a[m] = *(const short8*)(lA + SWZB(row0 + m * 16, ks * 64 + kslot));
#pragma unroll
        for (int n = 0; n < 4; ++n)
            b[n] = *(const short8*)(lB + SWZB(nrow0 + n * 16, ks * 64 + kslot));
#pragma unroll
        for (int m = 0; m < 4; ++m)
#pragma unroll
            for (int n = 0; n < 4; ++n)
                acc[m][n] = __builtin_amdgcn_mfma_f32_16x16x32_bf16(a[m], b[n], acc[m][n], 0, 0, 0);
    }
}

// ---------------- GEMM1: u = edge_t2v @ W1_top  (M=16000,K=128,N=512) ----------------
__global__ __launch_bounds__(256) void k_gemm1(const float* __restrict__ et2v,
                                               const ushort* __restrict__ W1t,
                                               ushort* __restrict__ u) {
    __shared__ __align__(16) unsigned char lA[16384];
    __shared__ __align__(16) unsigned char lB[16384];
    const int t = threadIdx.x;
    const int m0 = (blockIdx.x >> 2) * 128;
    const int n0 = (blockIdx.x & 3) * 128;
    const int lane = t & 63, wid = t >> 6, wr = wid >> 1, wc = wid & 1;
    const int srow = t >> 1, koff = (t & 1) * 32, lb0 = (t & 1) * 64;
    f32x4 acc[4][4] = {};
    for (int step = 0; step < 2; ++step) {
        const float4* ap = (const float4*)(et2v + (size_t)(m0 + srow) * 128 + step * 64 + koff);
#pragma unroll
        for (int i = 0; i < 4; ++i) {
            float4 x0 = ap[2 * i], x1 = ap[2 * i + 1];
            *(uint4*)&lA[SWZB(srow, lb0 + i * 16)] =
                make_uint4(pk2(x0.x, x0.y), pk2(x0.z, x0.w), pk2(x1.x, x1.y), pk2(x1.z, x1.w));
        }
        const uint4* bp = (const uint4*)(W1t + (size_t)(n0 + srow) * 128 + step * 64 + koff);
#pragma unroll
        for (int i = 0; i < 4; ++i) *(uint4*)&lB[SWZB(srow, lb0 + i * 16)] = bp[i];
        __syncthreads();
        mfma_step(lA, lB, wr, wc, lane, acc);
        __syncthreads();
    }
    const int rbase = wr * 64 + ((lane >> 4) << 2);
    const int cbase = n0 + wc * 64 + (lane & 15);
#pragma unroll
    for (int mm = 0; mm < 4; ++mm)
#pragma unroll
        for (int nn = 0; nn < 4; ++nn)
#pragma unroll
            for (int i = 0; i < 4; ++i)
                u[(size_t)(m0 + rbase + mm * 16 + i) * 512 + cbase + nn * 16] =
                    f2bf(acc[mm][nn][i]);
}

// ---------------- GEMM2: h2 = relu(relu(u+v_b) @ W2 + b2)  (M=128000,K=512,N=256) ----------------
// BN=256: one block covers full N -> A-formation done once, 64 MFMA per barrier pair
__global__ __launch_bounds__(256) void k_gemm2(const ushort* __restrict__ u,
                                               const float* __restrict__ v_b,
                                               const ushort* __restrict__ W2t,
                                               const float* __restrict__ b2,
                                               ushort* __restrict__ h2) {
    __shared__ __align__(16) unsigned char lA[16384];
    __shared__ __align__(16) unsigned char lB[32768];
    const int t = threadIdx.x;
    const int m0 = blockIdx.x * 128;
    const int lane = t & 63, wid = t >> 6, wr = wid >> 1, wc = wid & 1;
    const int srow = t >> 1, koff = (t & 1) * 32, lb0 = (t & 1) * 64;
    const int ae = (m0 + srow) >> 3, ab = (m0 + srow) & 7;
    f32x4 acc[4][8] = {};
    for (int step = 0; step < 8; ++step) {
        const int k0 = step * 64;
        const uint4* up = (const uint4*)(u + (size_t)ae * 512 + k0 + koff);
        const float4* vp = (const float4*)(v_b + ab * 512 + k0 + koff);
#pragma unroll
        for (int i = 0; i < 4; ++i) {
            uint4 uv = up[i];
            float4 va = vp[2 * i], vb4 = vp[2 * i + 1];
            unsigned r0 = pk2(fmaxf(bflo(uv.x) + va.x, 0.f), fmaxf(bfhi(uv.x) + va.y, 0.f));
            unsigned r1 = pk2(fmaxf(bflo(uv.y) + va.z, 0.f), fmaxf(bfhi(uv.y) + va.w, 0.f));
            unsigned r2 = pk2(fmaxf(bflo(uv.z) + vb4.x, 0.f), fmaxf(bfhi(uv.z) + vb4.y, 0.f));
            unsigned r3 = pk2(fmaxf(bflo(uv.w) + vb4.z, 0.f), fmaxf(bfhi(uv.w) + vb4.w, 0.f));
            *(uint4*)&lA[SWZB(srow, lb0 + i * 16)] = make_uint4(r0, r1, r2, r3);
        }
        const uint4* bp = (const uint4*)(W2t + (size_t)t * 512 + k0);
#pragma unroll
        for (int i = 0; i < 8; ++i) *(uint4*)&lB[SWZB(t, i * 16)] = bp[i];
        __syncthreads();
        {
            const int row0 = wr * 64 + (lane & 15);
            const int nrow0 = wc * 128 + (lane & 15);
            const int kslot = (lane >> 4) * 16;
#pragma unroll
            for (int ks = 0; ks < 2; ++ks) {
                short8 a[4], b[8];
#pragma unroll
                for (int m = 0; m < 4; ++m)
                    a[m] = *(const short8*)(lA + SWZB(row0 + m * 16, ks * 64 + kslot));
#pragma unroll
                for (int n = 0; n < 8; ++n)
                    b[n] = *(const short8*)(lB + SWZB(nrow0 + n * 16, ks * 64 + kslot));
#pragma unroll
                for (int m = 0; m < 4; ++m)
#pragma unroll
                    for (int n = 0; n < 8; ++n)
                        acc[m][n] = __builtin_amdgcn_mfma_f32_16x16x32_bf16(a[m], b[n], acc[m][n], 0, 0, 0);
            }
        }
        __syncthreads();
    }
    const int rbase = wr * 64 + ((lane >> 4) << 2);
    const int cbase = wc * 128 + (lane & 15);
#pragma unroll
    for (int nn = 0; nn < 8; ++nn) {
        const int gc = cbase + nn * 16;
        const float bb = b2[gc];
#pragma unroll
        for (int mm = 0; mm < 4; ++mm)
#pragma unroll
            for (int i = 0; i < 4; ++i)
                h2[(size_t)(m0 + rbase + mm * 16 + i) * 256 + gc] =
                    f2bf(fmaxf(acc[mm][nn][i] + bb, 0.f));
    }
}

// ---------------- GEMM3: tau = h2@W3+b3; x_ss = h_n[src]+tau; x_ee = rel+tau ----------------
__global__ __launch_bounds__(256) void k_gemm3(const ushort* __restrict__ h2,
                                               const ushort* __restrict__ W3t,
                                               const float* __restrict__ b3,
                                               const int* __restrict__ src,
                                               const int* __restrict__ rtyp,
                                               const float* __restrict__ h_n,
                                               const float* __restrict__ rel_embed,
                                               ushort* __restrict__ xss,
                                               ushort* __restrict__ xee) {
    __shared__ __align__(16) unsigned char lA[16384];
    __shared__ __align__(16) unsigned char lB[16384];
    const int t = threadIdx.x;
    const int m0 = blockIdx.x * 128;
    const int lane = t & 63, wid = t >> 6, wr = wid >> 1, wc = wid & 1;
    const int srow = t >> 1, koff = (t & 1) * 32, lb0 = (t & 1) * 64;
    f32x4 acc[4][4] = {};
    for (int step = 0; step < 4; ++step) {
        const int k0 = step * 64 + koff;
        const uint4* ap = (const uint4*)(h2 + (size_t)(m0 + srow) * 256 + k0);
#pragma unroll
        for (int i = 0; i < 4; ++i) *(uint4*)&lA[SWZB(srow, lb0 + i * 16)] = ap[i];
        const uint4* bp = (const uint4*)(W3t + (size_t)srow * 256 + k0);
#pragma unroll
        for (int i = 0; i < 4; ++i) *(uint4*)&lB[SWZB(srow, lb0 + i * 16)] = bp[i];
        __syncthreads();
        mfma_step(lA, lB, wr, wc, lane, acc);
        __syncthreads();
    }
    const int rbase = wr * 64 + ((lane >> 4) << 2);
    const int cbase = wc * 64 + (lane & 15);
#pragma unroll
    for (int mm = 0; mm < 4; ++mm)
#pragma unroll
        for (int i = 0; i < 4; ++i) {
            const int gr = m0 + rbase + mm * 16 + i;
            const int e = gr >> 3;
            const int se = src[e], rr = rtyp[e];
#pragma unroll
            for (int nn = 0; nn < 4; ++nn) {
                const int gc = cbase + nn * 16;
                const float tau = acc[mm][nn][i] + b3[gc];
                xss[(size_t)gr * 128 + gc] = f2bf(h_n[se * 128 + gc] + tau);
                xee[(size_t)gr * 128 + gc] = f2bf(rel_embed[rr * 128 + gc] + tau);
            }
        }
}

// ---------------- GEMM4: g = masked GEMMs + biases (no atomics) ----------------
__global__ __launch_bounds__(256) void k_gemm4(const ushort* __restrict__ xss,
                                               const ushort* __restrict__ xee,
                                               const ushort* __restrict__ Wallt,
                                               const float* __restrict__ bss,
                                               const float* __restrict__ bee,
                                               const int* __restrict__ edge_start,
                                               const int* __restrict__ edge_end,
                                               const int* __restrict__ batch_start,
                                               const int* __restrict__ batch_end,
                                               ushort* __restrict__ g_e) {
    __shared__ __align__(16) unsigned char lA[16384];
    __shared__ __align__(16) unsigned char lB[16384];
    __shared__ int selss_s[128], selee_s[128];
    __shared__ int am_s;
    const int t = threadIdx.x;
    const int m0 = blockIdx.x * 128;
    const int lane = t & 63, wid = t >> 6, wr = wid >> 1, wc = wid & 1;
    const int srow = t >> 1, koff = (t & 1) * 32, lb0 = (t & 1) * 64;
    if (t == 0) am_s = 0;
    __syncthreads();
    if (t < 128) {
        const int gr = m0 + t, e = gr >> 3, b = gr & 7;
        const int ss = sgnk(edge_start[e], batch_start[b]);
        const int se = sgnk(edge_end[e], batch_end[b]);
        selss_s[t] = ss; selee_s[t] = se;
        atomicOr(&am_s, (1 << ss) | (8 << se));
    }
    __syncthreads();
    const int am = am_s;
    f32x4 acc[4][4] = {};
    for (int step = 0; step < 12; ++step) {
        const int c = step >> 1;
        if (!((am >> c) & 1)) continue;   // block-uniform skip
        const int m3 = (c < 3) ? c : c - 3;
        const ushort* xsrc = (c < 3) ? xss : xee;
        const int sel = (c < 3) ? selss_s[srow] : selee_s[srow];
        const bool on = (sel == m3);
        const uint4* ap = (const uint4*)(xsrc + (size_t)(m0 + srow) * 128 + (step & 1) * 64 + koff);
#pragma unroll
        for (int i = 0; i < 4; ++i) {
            uint4 v = make_uint4(0u, 0u, 0u, 0u);
            if (on) v = ap[i];
            *(uint4*)&lA[SWZB(srow, lb0 + i * 16)] = v;
        }
        const uint4* bp = (const uint4*)(Wallt + (size_t)c * 16384 + (size_t)srow * 128 + (step & 1) * 64 + koff);
#pragma unroll
        for (int i = 0; i < 4; ++i) *(uint4*)&lB[SWZB(srow, lb0 + i * 16)] = bp[i];
        __syncthreads();
        mfma_step(lA, lB, wr, wc, lane, acc);
        __syncthreads();
    }
    const int rbase = wr * 64 + ((lane >> 4) << 2);
    const int cbase = wc * 64 + (lane & 15);
#pragma unroll
    for (int mm = 0; mm < 4; ++mm)
#pragma unroll
        for (int i = 0; i < 4; ++i) {
            const int r = rbase + mm * 16 + i;
            const int gr = m0 + r;
            const int ss = selss_s[r], se = selee_s[r];
#pragma unroll
            for (int nn = 0; nn < 4; ++nn) {
                const int gc = cbase + nn * 16;
                const float g = acc[mm][nn][i] + bss[ss * 128 + gc] + bee[se * 128 + gc];
                g_e[(size_t)gr * 128 + gc] = f2bf(g);
            }
        }
}

// ---------------- segment softmax (gather, no atomics): block = dst node ----------------
__global__ __launch_bounds__(128) void k_segsm(const int* __restrict__ rowptr,
                                               const int* __restrict__ ecsr,
                                               const float* __restrict__ wdst,
                                               const ushort* __restrict__ g_e,
                                               float* __restrict__ out) {
    const int n = blockIdx.x, d = threadIdx.x;
    const float w = wdst[n * 128 + d];
    const int s0 = rowptr[n], s1 = rowptr[n + 1];
    float m[8], z[8], S[8];
#pragma unroll
    for (int b = 0; b < 8; ++b) { m[b] = -1e30f; z[b] = 0.f; S[b] = 0.f; }
    for (int i = s0; i < s1; ++i) {
        const int e = ecsr[i];
        const ushort* gp = g_e + (size_t)e * 1024 + d;
#pragma unroll
        for (int b = 0; b < 8; ++b) {
            float g = bf2f(gp[b * 128]);
            float sc = leaky(w * g);
            float nm = fmaxf(m[b], sc);
            float sca = __expf(m[b] - nm);
            float s = __expf(sc - nm);
            z[b] = z[b] * sca + s;
            S[b] = S[b] * sca + s * g;
            m[b] = nm;
        }
    }
#pragma unroll
    for (int b = 0; b < 8; ++b) {
        float r = S[b] / (z[b] + 1e-16f);
        out[((size_t)n * 8 + b) * 128 + d] = leaky(r);
    }
}

extern "C" void kernel_launch(void* const* d_in, const int* in_sizes, int n_in,
                              void* d_out, int out_size, void* d_ws, size_t ws_size,
                              hipStream_t stream) {
    const int* src = (const int*)d_in[0];
    const int* dst = (const int*)d_in[1];
    const int* node_idx = (const int*)d_in[2];
    const int* rel = (const int*)d_in[3];
    const int* es = (const int*)d_in[4];
    const int* eend = (const int*)d_in[5];
    const int* bs = (const int*)d_in[6];
    const int* be = (const int*)d_in[7];
    const float* node_time = (const float*)d_in[8];
    const float* edge_t2v = (const float*)d_in[9];
    const float* batch_t2v = (const float*)d_in[10];
    const float* syn = (const float*)d_in[11];
    const float* diae = (const float*)d_in[12];
    const float* diaw = (const float*)d_in[13];
    const float* diab = (const float*)d_in[14];
    const float* rele = (const float*)d_in[15];
    const float* W1 = (const float*)d_in[16];
    const float* b1 = (const float*)d_in[17];
    const float* W2 = (const float*)d_in[18];
    const float* b2 = (const float*)d_in[19];
    const float* W3 = (const float*)d_in[20];
    const float* b3 = (const float*)d_in[21];
    const float* Wss = (const float*)d_in[22];
    const float* bss = (const float*)d_in[23];
    const float* Wee = (const float*)d_in[24];
    const float* bee = (const float*)d_in[25];
    const float* ai = (const float*)d_in[26];
    const float* aj = (const float*)d_in[27];

    float* ws = (float*)d_ws;
    ushort* h2 = (ushort*)(ws + OFF_H2);
    ushort* u = (ushort*)(ws + OFF_U);
    ushort* xss = (ushort*)(ws + OFF_XSS);
    ushort* xee = (ushort*)(ws + OFF_XEE);
    ushort* g_e = (ushort*)(ws + OFF_G);
    float* h_n = ws + OFF_HN;
    float* wdst = ws + OFF_WDST;
    float* v_b = ws + OFF_VB;
    ushort* W2t = (ushort*)(ws + OFF_W2T);
    ushort* W3t = (ushort*)(ws + OFF_W3T);
    ushort* Wallt = (ushort*)(ws + OFF_WALLT);
    ushort* W1t = (ushort*)(ws + OFF_W1T);
    int* cnt = (int*)(ws + OFF_CNT);
    int* rowptr = (int*)(ws + OFF_ROWP);
    int* cursor = (int*)(ws + OFF_CUR);
    int* ecsr = (int*)(ws + OFF_ECSR);
    float* out = (float*)d_out;

    hipMemsetAsync(cnt, 0, N_NODES * sizeof(int), stream);
    k_count<<<63, 256, 0, stream>>>(dst, cnt);
    k_scan<<<1, 256, 0, stream>>>(cnt, rowptr, cursor);
    k_scatter<<<63, 256, 0, stream>>>(dst, cursor, ecsr);

    k_wprep<<<1280, 256, 0, stream>>>(W1, W2, W3, Wss, Wee, W1t, W2t, W3t, Wallt);
    k_node<<<N_NODES, 128, 0, stream>>>(node_idx, node_time, syn, diae, diaw, diab, ai, aj, h_n, wdst);
    k_vb<<<B_Q, 512, 0, stream>>>(batch_t2v, W1, b1, v_b);
    k_gemm1<<<500, 256, 0, stream>>>(edge_t2v, W1t, u);
    k_gemm2<<<1000, 256, 0, stream>>>(u, v_b, W2t, b2, h2);
    k_gemm3<<<1000, 256, 0, stream>>>(h2, W3t, b3, src, rel, h_n, rele, xss, xee);
    k_gemm4<<<1000, 256, 0, stream>>>(xss, xee, Wallt, bss, bee, es, eend, bs, be, g_e);
    k_segsm<<<N_NODES, 128, 0, stream>>>(rowptr, ecsr, wdst, g_e, out);
}

// Round 7
// 339.000 us; speedup vs baseline: 4.1536x; 1.2086x over previous
//
#include <hip/hip_runtime.h>
#include <hip/hip_bf16.h>

typedef __attribute__((ext_vector_type(8))) short short8;
typedef __attribute__((ext_vector_type(4))) float f32x4;

#define N_NODES 5000
#define E_EDGES 16000
#define B_Q 8
#define D_DIM 128

// ---- ws layout (float offsets) ----
#define OFF_U     0            // bf16  8,192,000 (gemm1 -> mega)
#define OFF_G     4096000      // bf16 16,384,000 (mega -> segsm)
#define OFF_HN    12288000     // f32 640,000
#define OFF_WDST  12928000     // f32 640,000
#define OFF_VB    13568000     // f32 4,096
#define OFF_W1T   13572096     // bf16 65,536
#define OFF_W2T   13604864     // bf16 131,072
#define OFF_W3T   13670400     // bf16 32,768
#define OFF_WALLT 13686784     // bf16 98,304
#define OFF_CNT   13735936     // int 5,000
#define OFF_ROWP  13740936     // int 5,001
#define OFF_CUR   13745937     // int 5,000
#define OFF_ECSR  13750937     // int 16,000
// end = 13,766,937 floats = 55.1 MB

__device__ __forceinline__ float leaky(float x) { return x > 0.f ? x : 0.01f * x; }
__device__ __forceinline__ int sgnk(int a, int b) { int d = a - b; return d > 0 ? 2 : (d == 0 ? 1 : 0); }
__device__ __forceinline__ unsigned short f2bf(float f) {
    __hip_bfloat16 h = __float2bfloat16(f);
    unsigned short r; __builtin_memcpy(&r, &h, 2); return r;
}
__device__ __forceinline__ unsigned pk2(float a, float b) {
    return (unsigned)f2bf(a) | ((unsigned)f2bf(b) << 16);
}
__device__ __forceinline__ float bflo(unsigned w) { return __uint_as_float(w << 16); }
__device__ __forceinline__ float bfhi(unsigned w) { return __uint_as_float(w & 0xffff0000u); }
__device__ __forceinline__ float bf2f(unsigned short s) { return __uint_as_float(((unsigned)s) << 16); }

// XOR swizzles: byte ^= (row&7)<<4, row strides 128/256/512 B
#define SWZB(row, lb)  (((row) << 7) + ((lb) ^ (((row) & 7) << 4)))
#define SWZ256(row, lb) (((row) << 8) + ((lb) ^ (((row) & 7) << 4)))
#define SWZ512(row, lb) (((row) << 9) + ((lb) ^ (((row) & 7) << 4)))

// ---------------- prep kernels ----------------
__global__ void k_wprep(const float* __restrict__ W1, const float* __restrict__ W2,
                        const float* __restrict__ W3, const float* __restrict__ Wss,
                        const float* __restrict__ Wee,
                        ushort* __restrict__ W1t, ushort* __restrict__ W2t,
                        ushort* __restrict__ W3t, ushort* __restrict__ Wallt) {
    int tid = blockIdx.x * 256 + threadIdx.x;
    if (tid < 131072) {                       // W2t[n][k] = W2[k][n], 256x512
        int n = tid >> 9, k = tid & 511;
        W2t[tid] = f2bf(W2[k * 256 + n]);
    } else if (tid < 163840) {                // W3t[n][k] = W3[k][n], 128x256
        int q = tid - 131072; int n = q >> 8, k = q & 255;
        W3t[q] = f2bf(W3[k * 128 + n]);
    } else if (tid < 262144) {                // Wallt[c][n][k], c = {ss0..2, ee0..2}
        int q = tid - 163840; int c = q >> 14, rr = q & 16383, n = rr >> 7, k = rr & 127;
        const float* Wm = (c < 3) ? Wss : Wee; int cc = (c < 3) ? c : c - 3;
        Wallt[q] = f2bf(Wm[cc * 16384 + k * 128 + n]);
    } else if (tid < 327680) {                // W1t[n][k] = W1[k][n], 512x128 (top half)
        int q = tid - 262144; int n = q >> 7, k = q & 127;
        W1t[q] = f2bf(W1[k * 512 + n]);
    }
}

__global__ void k_node(const int* __restrict__ node_idx, const float* __restrict__ node_time,
                       const float* __restrict__ syn, const float* __restrict__ diae,
                       const float* __restrict__ diaw, const float* __restrict__ diab,
                       const float* __restrict__ attn_i, const float* __restrict__ attn_j,
                       float* __restrict__ h_n, float* __restrict__ w_dst) {
    int n = blockIdx.x, d = threadIdx.x;
    int nid = node_idx[n];
    float h = syn[nid * D_DIM + d];
    if (d >= 64) {
        int q = d - 64;
        h += diae[nid * 64 + q] * sinf(diaw[nid * 64 + q] * node_time[n] + diab[nid * 64 + q]);
    }
    h_n[n * D_DIM + d] = h;
    w_dst[n * D_DIM + d] = h * attn_i[d] * attn_j[d];
}

__global__ void k_vb(const float* __restrict__ bt2v, const float* __restrict__ W1,
                     const float* __restrict__ b1, float* __restrict__ v_b) {
    int b = blockIdx.x, j = threadIdx.x;
    float acc = b1[j];
    for (int i = 0; i < 128; ++i)
        acc = fmaf(bt2v[b * 128 + i], W1[(128 + i) * 512 + j], acc);
    v_b[b * 512 + j] = acc;
}

// ---------------- CSR build ----------------
__global__ void k_count(const int* __restrict__ dst, int* __restrict__ cnt) {
    int e = blockIdx.x * 256 + threadIdx.x;
    if (e < E_EDGES) atomicAdd(&cnt[dst[e]], 1);
}

__global__ void k_scan(const int* __restrict__ cnt, int* __restrict__ rowptr,
                       int* __restrict__ cursor) {
    __shared__ int part[256];
    const int t = threadIdx.x;
    const int i0 = t * 20, i1 = min(N_NODES, i0 + 20);
    int s = 0;
    for (int i = i0; i < i1; ++i) s += cnt[i];
    part[t] = s;
    __syncthreads();
    for (int off = 1; off < 256; off <<= 1) {
        int v = (t >= off) ? part[t - off] : 0;
        __syncthreads();
        part[t] += v;
        __syncthreads();
    }
    int run = (t > 0) ? part[t - 1] : 0;
    for (int i = i0; i < i1; ++i) { rowptr[i] = run; cursor[i] = run; run += cnt[i]; }
    if (i0 < N_NODES && i1 == N_NODES) rowptr[N_NODES] = run;
}

__global__ void k_scatter(const int* __restrict__ dst, int* __restrict__ cursor,
                          int* __restrict__ ecsr) {
    int e = blockIdx.x * 256 + threadIdx.x;
    if (e < E_EDGES) {
        int p = atomicAdd(&cursor[dst[e]], 1);
        ecsr[p] = e;
    }
}

// ---------------- shared 4x4 MFMA step (128B-row tiles) ----------------
__device__ __forceinline__ void mfma_step(const unsigned char* lA, const unsigned char* lB,
                                          int wr, int wc, int lane, f32x4 (&acc)[4][4]) {
    const int row0 = wr * 64 + (lane & 15);
    const int nrow0 = wc * 64 + (lane & 15);
    const int kslot = (lane >> 4) * 16;
#pragma unroll
    for (int ks = 0; ks < 2; ++ks) {
        short8 a[4], b[4];
#pragma unroll
        for (int m = 0; m < 4; ++m)
            a[m] = *(const short8*)(lA + SWZB(row0 + m * 16, ks * 64 + kslot));
#pragma unroll
        for (int n = 0; n < 4; ++n)
            b[n] = *(const short8*)(lB + SWZB(nrow0 + n * 16, ks * 64 + kslot));
#pragma unroll
        for (int m = 0; m < 4; ++m)
#pragma unroll
            for (int n = 0; n < 4; ++n)
                acc[m][n] = __builtin_amdgcn_mfma_f32_16x16x32_bf16(a[m], b[n], acc[m][n], 0, 0, 0);
    }
}

// ---------------- GEMM1: u = edge_t2v @ W1_top  (M=16000,K=128,N=512) ----------------
__global__ __launch_bounds__(256) void k_gemm1(const float* __restrict__ et2v,
                                               const ushort* __restrict__ W1t,
                                               ushort* __restrict__ u) {
    __shared__ __align__(16) unsigned char lA[16384];
    __shared__ __align__(16) unsigned char lB[16384];
    const int t = threadIdx.x;
    const int m0 = (blockIdx.x >> 2) * 128;
    const int n0 = (blockIdx.x & 3) * 128;
    const int lane = t & 63, wid = t >> 6, wr = wid >> 1, wc = wid & 1;
    const int srow = t >> 1, koff = (t & 1) * 32, lb0 = (t & 1) * 64;
    f32x4 acc[4][4] = {};
    for (int step = 0; step < 2; ++step) {
        const float4* ap = (const float4*)(et2v + (size_t)(m0 + srow) * 128 + step * 64 + koff);
#pragma unroll
        for (int i = 0; i < 4; ++i) {
            float4 x0 = ap[2 * i], x1 = ap[2 * i + 1];
            *(uint4*)&lA[SWZB(srow, lb0 + i * 16)] =
                make_uint4(pk2(x0.x, x0.y), pk2(x0.z, x0.w), pk2(x1.x, x1.y), pk2(x1.z, x1.w));
        }
        const uint4* bp = (const uint4*)(W1t + (size_t)(n0 + srow) * 128 + step * 64 + koff);
#pragma unroll
        for (int i = 0; i < 4; ++i) *(uint4*)&lB[SWZB(srow, lb0 + i * 16)] = bp[i];
        __syncthreads();
        mfma_step(lA, lB, wr, wc, lane, acc);
        __syncthreads();
    }
    const int rbase = wr * 64 + ((lane >> 4) << 2);
    const int cbase = n0 + wc * 64 + (lane & 15);
#pragma unroll
    for (int mm = 0; mm < 4; ++mm)
#pragma unroll
        for (int nn = 0; nn < 4; ++nn)
#pragma unroll
            for (int i = 0; i < 4; ++i)
                u[(size_t)(m0 + rbase + mm * 16 + i) * 512 + cbase + nn * 16] =
                    f2bf(acc[mm][nn][i]);
}

// ---------------- MEGA: gemm2+gemm3+gemm4 fused, block = 128 (e,b) rows ----------------
__global__ __launch_bounds__(256, 2) void k_mega(
    const ushort* __restrict__ u, const float* __restrict__ v_b,
    const ushort* __restrict__ W2t, const float* __restrict__ b2,
    const ushort* __restrict__ W3t, const float* __restrict__ b3,
    const ushort* __restrict__ Wallt,
    const float* __restrict__ bss, const float* __restrict__ bee,
    const int* __restrict__ src, const int* __restrict__ rtyp,
    const int* __restrict__ edge_start, const int* __restrict__ edge_end,
    const int* __restrict__ batch_start, const int* __restrict__ batch_end,
    const float* __restrict__ h_n, const float* __restrict__ rel_embed,
    ushort* __restrict__ g_e) {
    __shared__ __align__(16) unsigned char lds[65536];
    __shared__ int selss_s[128], selee_s[128];
    __shared__ int am_s;
    const int t = threadIdx.x;
    const int m0 = blockIdx.x * 128;
    const int lane = t & 63, wid = t >> 6, wr = wid >> 1, wc = wid & 1;
    const int srow = t >> 1, koff = (t & 1) * 32, lb0 = (t & 1) * 64;
    const int l15 = lane & 15;
    const int ls4 = (lane >> 4) << 2;
    const int kslot = (lane >> 4) * 16;   // byte offset of lane's k-group
    const int kslot8 = (lane >> 4) * 8;   // element offset

    if (t == 0) am_s = 0;
    __syncthreads();
    if (t < 128) {
        const int gr = m0 + t, e = gr >> 3, b = gr & 7;
        const int ss = sgnk(edge_start[e], batch_start[b]);
        const int se = sgnk(edge_end[e], batch_end[b]);
        selss_s[t] = ss; selee_s[t] = se;
        atomicOr(&am_s, (1 << ss) | (8 << se));
    }

    // ======== phase A: h2acc = relu(u+v_b) @ W2  (K=512, N=256 in regs) ========
    unsigned char* lA = lds;           // 16KB: 128 rows x 128B
    unsigned char* lB = lds + 16384;   // 32KB: 256 rows x 128B
    const int ae = (m0 + srow) >> 3, ab = (m0 + srow) & 7;
    f32x4 acc2[4][8] = {};
    for (int step = 0; step < 8; ++step) {
        const int k0 = step * 64;
        const uint4* up = (const uint4*)(u + (size_t)ae * 512 + k0 + koff);
        const float4* vp = (const float4*)(v_b + ab * 512 + k0 + koff);
#pragma unroll
        for (int i = 0; i < 4; ++i) {
            uint4 uv = up[i];
            float4 va = vp[2 * i], vb4 = vp[2 * i + 1];
            unsigned r0 = pk2(fmaxf(bflo(uv.x) + va.x, 0.f), fmaxf(bfhi(uv.x) + va.y, 0.f));
            unsigned r1 = pk2(fmaxf(bflo(uv.y) + va.z, 0.f), fmaxf(bfhi(uv.y) + va.w, 0.f));
            unsigned r2 = pk2(fmaxf(bflo(uv.z) + vb4.x, 0.f), fmaxf(bfhi(uv.z) + vb4.y, 0.f));
            unsigned r3 = pk2(fmaxf(bflo(uv.w) + vb4.z, 0.f), fmaxf(bfhi(uv.w) + vb4.w, 0.f));
            *(uint4*)&lA[SWZB(srow, lb0 + i * 16)] = make_uint4(r0, r1, r2, r3);
        }
        const uint4* bp = (const uint4*)(W2t + (size_t)t * 512 + k0);
#pragma unroll
        for (int i = 0; i < 8; ++i) *(uint4*)&lB[SWZB(t, i * 16)] = bp[i];
        __syncthreads();
        {
            const int row0 = wr * 64 + l15;
            const int nrow0 = wc * 128 + l15;
#pragma unroll
            for (int ks = 0; ks < 2; ++ks) {
                short8 a[4], b[8];
#pragma unroll
                for (int m = 0; m < 4; ++m)
                    a[m] = *(const short8*)(lA + SWZB(row0 + m * 16, ks * 64 + kslot));
#pragma unroll
                for (int n = 0; n < 8; ++n)
                    b[n] = *(const short8*)(lB + SWZB(nrow0 + n * 16, ks * 64 + kslot));
#pragma unroll
                for (int m = 0; m < 4; ++m)
#pragma unroll
                    for (int n = 0; n < 8; ++n)
                        acc2[m][n] = __builtin_amdgcn_mfma_f32_16x16x32_bf16(a[m], b[n], acc2[m][n], 0, 0, 0);
            }
        }
        __syncthreads();
    }

    // ======== h2 tile to LDS (64KB, rows 128 x 512B, swizzled) ========
    const int rb = wr * 64 + ls4;      // + mm*16 + i
    const int cb2 = wc * 128 + l15;    // + nn*16   (k in 0..255)
    float b2r[8];
#pragma unroll
    for (int nn = 0; nn < 8; ++nn) b2r[nn] = b2[cb2 + nn * 16];
#pragma unroll
    for (int mm = 0; mm < 4; ++mm)
#pragma unroll
        for (int i = 0; i < 4; ++i) {
            const int r = rb + mm * 16 + i;
#pragma unroll
            for (int nn = 0; nn < 8; ++nn) {
                const int k = cb2 + nn * 16;
                *(ushort*)&lds[SWZ512(r, 2 * k)] =
                    f2bf(fmaxf(acc2[mm][nn][i] + b2r[nn], 0.f));
            }
        }
    __syncthreads();

    // ======== phase B: tau = h2 @ W3t (K=256, N=128); B direct from L2 ========
    f32x4 tacc[4][4] = {};
#pragma unroll
    for (int ks = 0; ks < 8; ++ks) {
        short8 a[4], b[4];
#pragma unroll
        for (int m = 0; m < 4; ++m) {
            const int rA = wr * 64 + l15 + m * 16;
            a[m] = *(const short8*)&lds[SWZ512(rA, ks * 64 + kslot)];
        }
#pragma unroll
        for (int n = 0; n < 4; ++n) {
            const int nB = wc * 64 + l15 + n * 16;
            b[n] = *(const short8*)(W3t + nB * 256 + ks * 32 + kslot8);
        }
#pragma unroll
        for (int m = 0; m < 4; ++m)
#pragma unroll
            for (int n = 0; n < 4; ++n)
                tacc[m][n] = __builtin_amdgcn_mfma_f32_16x16x32_bf16(a[m], b[n], tacc[m][n], 0, 0, 0);
    }
    __syncthreads();   // h2 tile consumed

    // ======== epilogue B: xss/xee tiles (2 x 32KB, rows 128 x 256B) ========
    const int cb1 = wc * 64 + l15;     // + nn*16  (k2 in 0..127)
    float b3r[4];
#pragma unroll
    for (int nn = 0; nn < 4; ++nn) b3r[nn] = b3[cb1 + nn * 16];
#pragma unroll
    for (int mm = 0; mm < 4; ++mm)
#pragma unroll
        for (int i = 0; i < 4; ++i) {
            const int r = rb + mm * 16 + i;
            const int gr = m0 + r, e = gr >> 3;
            const int se = src[e], rr = rtyp[e];
#pragma unroll
            for (int nn = 0; nn < 4; ++nn) {
                const int k2 = cb1 + nn * 16;
                const float tau = tacc[mm][nn][i] + b3r[nn];
                *(ushort*)&lds[SWZ256(r, 2 * k2)] = f2bf(h_n[se * 128 + k2] + tau);
                *(ushort*)&lds[32768 + SWZ256(r, 2 * k2)] = f2bf(rel_embed[rr * 128 + k2] + tau);
            }
        }
    __syncthreads();

    // ======== phase C: g = sum of masked chunk GEMMs (K=128 each) ========
    int sel_ss[4], sel_ee[4];
#pragma unroll
    for (int m = 0; m < 4; ++m) {
        const int rA = wr * 64 + l15 + m * 16;
        sel_ss[m] = selss_s[rA]; sel_ee[m] = selee_s[rA];
    }
    const int am = am_s;
    const short8 zero8 = {0, 0, 0, 0, 0, 0, 0, 0};
    f32x4 gacc[4][4] = {};
    for (int c = 0; c < 6; ++c) {
        if (!((am >> c) & 1)) continue;
        const int m3 = (c < 3) ? c : c - 3;
        const int xb = (c < 3) ? 0 : 32768;
#pragma unroll
        for (int ks = 0; ks < 4; ++ks) {
            short8 a[4], b[4];
#pragma unroll
            for (int m = 0; m < 4; ++m) {
                const int rA = wr * 64 + l15 + m * 16;
                short8 v = *(const short8*)&lds[xb + SWZ256(rA, ks * 64 + kslot)];
                const int sel = (c < 3) ? sel_ss[m] : sel_ee[m];
                a[m] = (sel == m3) ? v : zero8;
            }
#pragma unroll
            for (int n = 0; n < 4; ++n) {
                const int nB = wc * 64 + l15 + n * 16;
                b[n] = *(const short8*)(Wallt + (size_t)c * 16384 + nB * 128 + ks * 32 + kslot8);
            }
#pragma unroll
            for (int m = 0; m < 4; ++m)
#pragma unroll
                for (int n = 0; n < 4; ++n)
                    gacc[m][n] = __builtin_amdgcn_mfma_f32_16x16x32_bf16(a[m], b[n], gacc[m][n], 0, 0, 0);
        }
    }
    __syncthreads();   // xss/xee tiles consumed

    // ======== epilogue C: g + biases -> LDS -> coalesced global store ========
#pragma unroll
    for (int mm = 0; mm < 4; ++mm)
#pragma unroll
        for (int i = 0; i < 4; ++i) {
            const int r = rb + mm * 16 + i;
            const int ss = selss_s[r], se = selee_s[r];
#pragma unroll
            for (int nn = 0; nn < 4; ++nn) {
                const int k2 = cb1 + nn * 16;
                const float g = gacc[mm][nn][i] + bss[ss * 128 + k2] + bee[se * 128 + k2];
                *(ushort*)&lds[SWZ256(r, 2 * k2)] = f2bf(g);
            }
        }
    __syncthreads();
    {
        const int r = srow, half = t & 1;
        const size_t gbase = (size_t)(m0 + r) * 128 + half * 64;
#pragma unroll
        for (int q = 0; q < 8; ++q) {
            uint4 v = *(const uint4*)&lds[SWZ256(r, half * 128 + q * 16)];
            *(uint4*)(g_e + gbase + q * 8) = v;
        }
    }
}

// ---------------- segment softmax (gather, no atomics): block = dst node ----------------
__global__ __launch_bounds__(128) void k_segsm(const int* __restrict__ rowptr,
                                               const int* __restrict__ ecsr,
                                               const float* __restrict__ wdst,
                                               const ushort* __restrict__ g_e,
                                               float* __restrict__ out) {
    const int n = blockIdx.x, d = threadIdx.x;
    const float w = wdst[n * 128 + d];
    const int s0 = rowptr[n], s1 = rowptr[n + 1];
    float m[8], z[8], S[8];
#pragma unroll
    for (int b = 0; b < 8; ++b) { m[b] = -1e30f; z[b] = 0.f; S[b] = 0.f; }
    for (int i = s0; i < s1; ++i) {
        const int e = ecsr[i];
        const ushort* gp = g_e + (size_t)e * 1024 + d;
#pragma unroll
        for (int b = 0; b < 8; ++b) {
            float g = bf2f(gp[b * 128]);
            float sc = leaky(w * g);
            float nm = fmaxf(m[b], sc);
            float sca = __expf(m[b] - nm);
            float s = __expf(sc - nm);
            z[b] = z[b] * sca + s;
            S[b] = S[b] * sca + s * g;
            m[b] = nm;
        }
    }
#pragma unroll
    for (int b = 0; b < 8; ++b) {
        float r = S[b] / (z[b] + 1e-16f);
        out[((size_t)n * 8 + b) * 128 + d] = leaky(r);
    }
}

extern "C" void kernel_launch(void* const* d_in, const int* in_sizes, int n_in,
                              void* d_out, int out_size, void* d_ws, size_t ws_size,
                              hipStream_t stream) {
    const int* src = (const int*)d_in[0];
    const int* dst = (const int*)d_in[1];
    const int* node_idx = (const int*)d_in[2];
    const int* rel = (const int*)d_in[3];
    const int* es = (const int*)d_in[4];
    const int* eend = (const int*)d_in[5];
    const int* bs = (const int*)d_in[6];
    const int* be = (const int*)d_in[7];
    const float* node_time = (const float*)d_in[8];
    const float* edge_t2v = (const float*)d_in[9];
    const float* batch_t2v = (const float*)d_in[10];
    const float* syn = (const float*)d_in[11];
    const float* diae = (const float*)d_in[12];
    const float* diaw = (const float*)d_in[13];
    const float* diab = (const float*)d_in[14];
    const float* rele = (const float*)d_in[15];
    const float* W1 = (const float*)d_in[16];
    const float* b1 = (const float*)d_in[17];
    const float* W2 = (const float*)d_in[18];
    const float* b2 = (const float*)d_in[19];
    const float* W3 = (const float*)d_in[20];
    const float* b3 = (const float*)d_in[21];
    const float* Wss = (const float*)d_in[22];
    const float* bss = (const float*)d_in[23];
    const float* Wee = (const float*)d_in[24];
    const float* bee = (const float*)d_in[25];
    const float* ai = (const float*)d_in[26];
    const float* aj = (const float*)d_in[27];

    float* ws = (float*)d_ws;
    ushort* u = (ushort*)(ws + OFF_U);
    ushort* g_e = (ushort*)(ws + OFF_G);
    float* h_n = ws + OFF_HN;
    float* wdst = ws + OFF_WDST;
    float* v_b = ws + OFF_VB;
    ushort* W1t = (ushort*)(ws + OFF_W1T);
    ushort* W2t = (ushort*)(ws + OFF_W2T);
    ushort* W3t = (ushort*)(ws + OFF_W3T);
    ushort* Wallt = (ushort*)(ws + OFF_WALLT);
    int* cnt = (int*)(ws + OFF_CNT);
    int* rowptr = (int*)(ws + OFF_ROWP);
    int* cursor = (int*)(ws + OFF_CUR);
    int* ecsr = (int*)(ws + OFF_ECSR);
    float* out = (float*)d_out;

    hipMemsetAsync(cnt, 0, N_NODES * sizeof(int), stream);
    k_count<<<63, 256, 0, stream>>>(dst, cnt);
    k_scan<<<1, 256, 0, stream>>>(cnt, rowptr, cursor);
    k_scatter<<<63, 256, 0, stream>>>(dst, cursor, ecsr);

    k_wprep<<<1280, 256, 0, stream>>>(W1, W2, W3, Wss, Wee, W1t, W2t, W3t, Wallt);
    k_node<<<N_NODES, 128, 0, stream>>>(node_idx, node_time, syn, diae, diaw, diab, ai, aj, h_n, wdst);
    k_vb<<<B_Q, 512, 0, stream>>>(batch_t2v, W1, b1, v_b);
    k_gemm1<<<500, 256, 0, stream>>>(edge_t2v, W1t, u);
    k_mega<<<1000, 256, 0, stream>>>(u, v_b, W2t, b2, W3t, b3, Wallt, bss, bee,
                                     src, rel, es, eend, bs, be, h_n, rele, g_e);
    k_segsm<<<N_NODES, 128, 0, stream>>>(rowptr, ecsr, wdst, g_e, out);
}